// Round 13
// baseline (313.289 us; speedup 1.0000x reference)
//
#include <hip/hip_runtime.h>
#include <hip/hip_bf16.h>
#include <math.h>

#define B_    32
#define J_    1182     // V*P = 6*197
#define D_    512
#define L_    77
#define C_    5
#define NBA_  16       // attention blocks_x per batch
#define NGRP_ 148      // ceil(1182/8) row-groups of 8
#define NCH_  19       // (unused legacy)

__device__ __forceinline__ float dot4(float4 a, float4 b) {
    return a.x*b.x + a.y*b.y + a.z*b.z + a.w*b.w;
}

__device__ __forceinline__ float wave_sum(float v) {
#pragma unroll
    for (int off = 32; off > 0; off >>= 1) v += __shfl_xor(v, off, 64);
    return v;
}

// K1: blocks 0..1371: cond_maps (o-major); block 1372: fn normalize + loss_dis
__global__ void k_setup(const float* __restrict__ fc, const float* __restrict__ cw,
                        const float* __restrict__ cb, float* __restrict__ cm,
                        float* __restrict__ fn, float* __restrict__ loss_out) {
    __shared__ float sfc[C_*D_];
    int t = threadIdx.x;
    for (int i = t; i < C_*D_; i += 256) sfc[i] = fc[i];
    __syncthreads();
    int wave = t >> 6, lane = t & 63;

    if (blockIdx.x == 1372) {
        for (int c = wave; c < C_; c += 4) {
            float ss = 0.f;
            for (int d = lane; d < D_; d += 64) { float v = sfc[c*D_+d]; ss += v*v; }
            ss = wave_sum(ss);
            float inv = 1.f / fmaxf(sqrtf(ss), 1e-12f);
            for (int d = lane; d < D_; d += 64) sfc[c*D_+d] *= inv;
        }
        __syncthreads();
        for (int i = t; i < C_*D_; i += 256) fn[i] = sfc[i];
        if (wave == 0) {
            float acc = 0.f;
            for (int i = 0; i < C_; ++i)
                for (int j = i+1; j < C_; ++j) {
                    float p = 0.f;
                    for (int d = lane; d < D_; d += 64) p += sfc[i*D_+d]*sfc[j*D_+d];
                    p = wave_sum(p);
                    acc += fmaxf(p, 0.f);
                }
            if (lane == 0) *loss_out = acc * (1.f/10.f);
        }
        return;
    }

    int o = blockIdx.x*4 + wave;         // < 5488
    const float4* w4 = (const float4*)(cw + (size_t)o*D_);
    float4 wa = w4[lane], wb = w4[lane+64];
    float bias = cb[o];
    float keep = 0.f;
#pragma unroll
    for (int c = 0; c < C_; ++c) {
        const float4* f4 = (const float4*)(sfc + c*D_);
        float s = dot4(wa, f4[lane]) + dot4(wb, f4[lane+64]);
        s = wave_sum(s);
        if (lane == c) keep = s;
    }
    if (lane < C_) cm[lane*5488 + o] = keep + bias;
}

// K2: 8 threads per (b,l) prompt row, 3-level shuffle reduce.
__global__ void k_sim(const float* __restrict__ fp, const float* __restrict__ fn,
                      float* __restrict__ swl) {
    int t = threadIdx.x;                 // 256 -> 32 rows/block
    int row = t >> 3, seg = t & 7;
    int bl = blockIdx.x*32 + row;        // grid 77 -> exactly 2464 rows
    int b = bl / L_, l = bl - b*L_;
    const float4* p4 = ((const float4*)(fp + (size_t)bl*D_)) + seg*16;
    const float4* f4 = ((const float4*)fn) + seg*16;
    float ss=0.f, s0=0.f, s1=0.f, s2=0.f, s3=0.f, s4=0.f;
#pragma unroll 4
    for (int k = 0; k < 16; ++k) {
        float4 v = p4[k];
        ss += dot4(v, v);
        s0 += dot4(v, f4[k]);
        s1 += dot4(v, f4[128+k]);
        s2 += dot4(v, f4[256+k]);
        s3 += dot4(v, f4[384+k]);
        s4 += dot4(v, f4[512+k]);
    }
#pragma unroll
    for (int off = 1; off < 8; off <<= 1) {
        ss += __shfl_xor(ss,off,64);
        s0 += __shfl_xor(s0,off,64); s1 += __shfl_xor(s1,off,64);
        s2 += __shfl_xor(s2,off,64); s3 += __shfl_xor(s3,off,64);
        s4 += __shfl_xor(s4,off,64);
    }
    if (seg == 0) {
        float inv = 1.f / fmaxf(sqrtf(ss), 1e-12f);
        float inv2 = inv*inv;
        swl[((size_t)(b*C_+0))*L_ + l] = s0*inv2;
        swl[((size_t)(b*C_+1))*L_ + l] = s1*inv2;
        swl[((size_t)(b*C_+2))*L_ + l] = s2*inv2;
        swl[((size_t)(b*C_+3))*L_ + l] = s3*inv2;
        swl[((size_t)(b*C_+4))*L_ + l] = s4*inv2;
    }
}

// K3: Q[b,c,d] = sum_l swl[b,c,l] * fp[b,l,d]
__global__ void k_Q(const float* __restrict__ fp, const float* __restrict__ swl,
                    float* __restrict__ Q) {
    __shared__ float sw[C_][80];
    int b = blockIdx.y;
    int t = threadIdx.x;
    for (int i = t; i < C_*L_; i += 256) { int c = i/L_, l = i - c*L_; sw[c][l] = swl[((size_t)(b*C_+c))*L_ + l]; }
    __syncthreads();
    int d = blockIdx.x*256 + t;
    float a0=0.f, a1=0.f, a2=0.f, a3=0.f, a4=0.f;
    const float* f = fp + (size_t)b*L_*D_ + d;
    for (int l = 0; l < L_; ++l) {
        float v = f[(size_t)l*D_];
        a0 += sw[0][l]*v; a1 += sw[1][l]*v; a2 += sw[2][l]*v;
        a3 += sw[3][l]*v; a4 += sw[4][l]*v;
    }
    Q[(size_t)(b*C_+0)*D_ + d] = a0;
    Q[(size_t)(b*C_+1)*D_ + d] = a1;
    Q[(size_t)(b*C_+2)*D_ + d] = a2;
    Q[(size_t)(b*C_+3)*D_ + d] = a3;
    Q[(size_t)(b*C_+4)*D_ + d] = a4;
}

// K4: SINGLE-PASS attention. grid (NBA_, B_), 256 thr (4 waves).
// Wave owns 8-row groups g = slot + 64*p (slot = bx*4+wave); per group:
//   score (8 thr/row, swizzled-qs LDS, 3-lvl shuffles) -> per-wave online
//   softmax (in-wave shuffles only, NO barriers) -> accumulate rows via
//   coalesced L1/L2-hot re-read into 10 named float4 accumulators.
// Barriers: qs stage + final 4-wave combine only.
__global__ void k_attn2(const float* __restrict__ tex, const float* __restrict__ Q,
                        float* __restrict__ part, float2* __restrict__ msum) {
    __shared__ float4 qs[C_*128];          // 10240 B, swizzled (c*16+k)*8+s
    __shared__ float4 comb[4][C_*2*64];    // 40960 B, [wave][c*128 + k*64 + lane]
    __shared__ float2 wms[4][C_];
    int bx = blockIdx.x, b = blockIdx.y;
    int t = threadIdx.x, wave = t >> 6, lane = t & 63;
    int r = lane >> 3, s = lane & 7;

    {
        const float4* q4 = (const float4*)(Q + (size_t)b*C_*D_);
        for (int i = t; i < C_*128; i += 256) {
            int c = i >> 7, f = i & 127;
            qs[(c*16 + (f & 15))*8 + (f >> 4)] = q4[i];
        }
    }
    __syncthreads();

    float4 a00=make_float4(0,0,0,0), a01=a00, a10=a00, a11=a00,
           a20=a00, a21=a00, a30=a00, a31=a00, a40=a00, a41=a00;
    float m0=-1e30f, m1=-1e30f, m2=-1e30f, m3=-1e30f, m4=-1e30f;
    float su0=0.f, su1=0.f, su2=0.f, su3=0.f, su4=0.f;

    int slot = bx*4 + wave;
    for (int g = slot; g < NGRP_; g += 64) {
        int j0 = g*8;
        int j  = j0 + r;
        bool valid = (j < J_);
        int jc = valid ? j : (J_-1);

        // ---- score phase (row-seg layout) ----
        const float4* tp = ((const float4*)(tex + ((size_t)(b*J_ + jc))*D_)) + s*16;
        float ss=0.f, s0=0.f, s1=0.f, s2=0.f, s3=0.f, s4=0.f;
#pragma unroll
        for (int k = 0; k < 16; ++k) {
            float4 v = tp[k];
            ss += dot4(v, v);
            s0 += dot4(v, qs[k*8 + s]);
            s1 += dot4(v, qs[128 + k*8 + s]);
            s2 += dot4(v, qs[256 + k*8 + s]);
            s3 += dot4(v, qs[384 + k*8 + s]);
            s4 += dot4(v, qs[512 + k*8 + s]);
        }
#pragma unroll
        for (int off = 1; off < 8; off <<= 1) {
            ss += __shfl_xor(ss,off,64);
            s0 += __shfl_xor(s0,off,64); s1 += __shfl_xor(s1,off,64);
            s2 += __shfl_xor(s2,off,64); s3 += __shfl_xor(s3,off,64);
            s4 += __shfl_xor(s4,off,64);
        }
        float inv = 1.f / fmaxf(sqrtf(ss), 1e-12f);
        s0 *= inv; s1 *= inv; s2 *= inv; s3 *= inv; s4 *= inv;

        // ---- per-wave online softmax (in-wave shuffles only) ----
        float n0 = valid ? s0 : -1e30f, n1 = valid ? s1 : -1e30f,
              n2 = valid ? s2 : -1e30f, n3 = valid ? s3 : -1e30f,
              n4 = valid ? s4 : -1e30f;
#pragma unroll
        for (int off = 8; off < 64; off <<= 1) {
            n0 = fmaxf(n0, __shfl_xor(n0,off,64));
            n1 = fmaxf(n1, __shfl_xor(n1,off,64));
            n2 = fmaxf(n2, __shfl_xor(n2,off,64));
            n3 = fmaxf(n3, __shfl_xor(n3,off,64));
            n4 = fmaxf(n4, __shfl_xor(n4,off,64));
        }
        float M0 = fmaxf(m0, n0), M1 = fmaxf(m1, n1), M2 = fmaxf(m2, n2),
              M3 = fmaxf(m3, n3), M4 = fmaxf(m4, n4);
        float f0 = expf(m0 - M0), f1 = expf(m1 - M1), f2 = expf(m2 - M2),
              f3 = expf(m3 - M3), f4 = expf(m4 - M4);
        float e0 = valid ? expf(s0 - M0) : 0.f;
        float e1 = valid ? expf(s1 - M1) : 0.f;
        float e2 = valid ? expf(s2 - M2) : 0.f;
        float e3 = valid ? expf(s3 - M3) : 0.f;
        float e4 = valid ? expf(s4 - M4) : 0.f;
        float q0 = (s==0)? e0 : 0.f, q1 = (s==0)? e1 : 0.f, q2 = (s==0)? e2 : 0.f,
              q3 = (s==0)? e3 : 0.f, q4_ = (s==0)? e4 : 0.f;
#pragma unroll
        for (int off = 1; off < 64; off <<= 1) {
            q0 += __shfl_xor(q0,off,64); q1 += __shfl_xor(q1,off,64);
            q2 += __shfl_xor(q2,off,64); q3 += __shfl_xor(q3,off,64);
            q4_ += __shfl_xor(q4_,off,64);
        }
        su0 = su0*f0 + q0; su1 = su1*f1 + q1; su2 = su2*f2 + q2;
        su3 = su3*f3 + q3; su4 = su4*f4 + q4_;
        m0 = M0; m1 = M1; m2 = M2; m3 = M3; m4 = M4;

        // rescale accumulators
        a00.x*=f0; a00.y*=f0; a00.z*=f0; a00.w*=f0;  a01.x*=f0; a01.y*=f0; a01.z*=f0; a01.w*=f0;
        a10.x*=f1; a10.y*=f1; a10.z*=f1; a10.w*=f1;  a11.x*=f1; a11.y*=f1; a11.z*=f1; a11.w*=f1;
        a20.x*=f2; a20.y*=f2; a20.z*=f2; a20.w*=f2;  a21.x*=f2; a21.y*=f2; a21.z*=f2; a21.w*=f2;
        a30.x*=f3; a30.y*=f3; a30.z*=f3; a30.w*=f3;  a31.x*=f3; a31.y*=f3; a31.z*=f3; a31.w*=f3;
        a40.x*=f4; a40.y*=f4; a40.z*=f4; a40.w*=f4;  a41.x*=f4; a41.y*=f4; a41.z*=f4; a41.w*=f4;

        // ---- accumulate (d-slice layout, coalesced L1/L2-hot re-read) ----
        const float4* tq = (const float4*)(tex + ((size_t)(b*J_ + j0))*D_);
        int rows = min(8, J_ - j0);
#pragma unroll
        for (int rr = 0; rr < 8; ++rr) {
            if (rr < rows) {
                float4 v0 = tq[rr*128 + lane];
                float4 v1 = tq[rr*128 + 64 + lane];
                float w0 = __shfl(e0, rr*8, 64);
                float w1 = __shfl(e1, rr*8, 64);
                float w2 = __shfl(e2, rr*8, 64);
                float w3 = __shfl(e3, rr*8, 64);
                float w4 = __shfl(e4, rr*8, 64);
                a00.x += v0.x*w0; a00.y += v0.y*w0; a00.z += v0.z*w0; a00.w += v0.w*w0;
                a01.x += v1.x*w0; a01.y += v1.y*w0; a01.z += v1.z*w0; a01.w += v1.w*w0;
                a10.x += v0.x*w1; a10.y += v0.y*w1; a10.z += v0.z*w1; a10.w += v0.w*w1;
                a11.x += v1.x*w1; a11.y += v1.y*w1; a11.z += v1.z*w1; a11.w += v1.w*w1;
                a20.x += v0.x*w2; a20.y += v0.y*w2; a20.z += v0.z*w2; a20.w += v0.w*w2;
                a21.x += v1.x*w2; a21.y += v1.y*w2; a21.z += v1.z*w2; a21.w += v1.w*w2;
                a30.x += v0.x*w3; a30.y += v0.y*w3; a30.z += v0.z*w3; a30.w += v0.w*w3;
                a31.x += v1.x*w3; a31.y += v1.y*w3; a31.z += v1.z*w3; a31.w += v1.w*w3;
                a40.x += v0.x*w4; a40.y += v0.y*w4; a40.z += v0.z*w4; a40.w += v0.w*w4;
                a41.x += v1.x*w4; a41.y += v1.y*w4; a41.z += v1.z*w4; a41.w += v1.w*w4;
            }
        }
    }

    // ---- epilogue: combine 4 waves with per-wave (m,s) fixup ----
    comb[wave][0*128 + 0*64 + lane] = a00;  comb[wave][0*128 + 64 + lane] = a01;
    comb[wave][1*128 + 0*64 + lane] = a10;  comb[wave][1*128 + 64 + lane] = a11;
    comb[wave][2*128 + 0*64 + lane] = a20;  comb[wave][2*128 + 64 + lane] = a21;
    comb[wave][3*128 + 0*64 + lane] = a30;  comb[wave][3*128 + 64 + lane] = a31;
    comb[wave][4*128 + 0*64 + lane] = a40;  comb[wave][4*128 + 64 + lane] = a41;
    if (lane == 0) {
        wms[wave][0] = make_float2(m0, su0);
        wms[wave][1] = make_float2(m1, su1);
        wms[wave][2] = make_float2(m2, su2);
        wms[wave][3] = make_float2(m3, su3);
        wms[wave][4] = make_float2(m4, su4);
    }
    __syncthreads();
    for (int idx = t; idx < C_*128; idx += 256) {
        int c = idx >> 7, f = idx & 127;
        float2 w0m = wms[0][c], w1m = wms[1][c], w2m = wms[2][c], w3m = wms[3][c];
        float mb = fmaxf(fmaxf(w0m.x, w1m.x), fmaxf(w2m.x, w3m.x));
        float x0 = expf(w0m.x - mb), x1 = expf(w1m.x - mb),
              x2 = expf(w2m.x - mb), x3 = expf(w3m.x - mb);
        float sden = w0m.y*x0 + w1m.y*x1 + w2m.y*x2 + w3m.y*x3;
        float4 c0 = comb[0][c*128+f], c1 = comb[1][c*128+f],
               c2 = comb[2][c*128+f], c3 = comb[3][c*128+f];
        float4 o;
        o.x = c0.x*x0 + c1.x*x1 + c2.x*x2 + c3.x*x3;
        o.y = c0.y*x0 + c1.y*x1 + c2.y*x2 + c3.y*x3;
        o.z = c0.z*x0 + c1.z*x1 + c2.z*x2 + c3.z*x3;
        o.w = c0.w*x0 + c1.w*x1 + c2.w*x2 + c3.w*x3;
        size_t pb = ((size_t)(bx*B_ + b)*C_ + c)*D_ + f*4;
        *(float4*)(part + pb) = o;
        if (f == 0) msum[(size_t)(bx*B_ + b)*C_ + c] = make_float2(mb, sden);
    }
}

// K5: fused[bc][d] = (sum_bx part[bx][bc][d] * w_bx) * eot[b][d]; 16-chunk fixup.
__global__ void k_reduce(const float* __restrict__ part, const float2* __restrict__ msum,
                         const float* __restrict__ eot, float* __restrict__ fused) {
    int idx = blockIdx.x*256 + threadIdx.x;   // < B*C*D = 81920
    int bc = idx >> 9; int d = idx & (D_-1); int b = bc / C_;
    float mg = -1e30f;
#pragma unroll
    for (int ch = 0; ch < NBA_; ++ch) mg = fmaxf(mg, msum[ch*(B_*C_) + bc].x);
    float denom = 0.f;
#pragma unroll
    for (int ch = 0; ch < NBA_; ++ch) {
        float2 v = msum[ch*(B_*C_) + bc];
        denom += v.y * expf(v.x - mg);
    }
    float invd = 1.f / denom;
    float s = 0.f;
#pragma unroll
    for (int ch = 0; ch < NBA_; ++ch)
        s += part[(size_t)ch*(B_*C_*D_) + idx] * (expf(msum[ch*(B_*C_) + bc].x - mg) * invd);
    fused[idx] = s * eot[b*D_ + d];
}

// K6: fq + TargetNet per (b,c) block.
__global__ void k_fq_target(const float* __restrict__ fused,
                            const float* __restrict__ qw, const float* __restrict__ qb,
                            const float* __restrict__ g1w, const float* __restrict__ g2w,
                            const float* __restrict__ g3w, const float* __restrict__ g4w,
                            const float* __restrict__ fcb, float* __restrict__ out) {
    int bc = blockIdx.x; int b = bc / C_; int c = bc - b*C_;
    __shared__ float sf[D_];
    __shared__ float sa[224], sb[112];
    int t = threadIdx.x;                 // 256

    sf[t]     = fused[(size_t)bc*D_ + t];
    sf[t+256] = fused[(size_t)bc*D_ + t + 256];
    __syncthreads();

    if (t < 224) {
        const float4* w4 = (const float4*)(qw + (size_t)t*D_);
        const float4* s4 = (const float4*)sf;
        float acc = 0.f;
#pragma unroll 4
        for (int i = 0; i < 128; ++i) acc += dot4(s4[i], w4[i]);
        sa[t] = acc + qb[t];
    }
    __syncthreads();

    if (t < 112) {
        const float* w = g1w + (size_t)c*25088 + t*224;
        float s = fcb[c*112 + t];
        for (int k = 0; k < 224; ++k) s += w[k]*sa[k];
        sb[t] = 1.f/(1.f+expf(-s));
    }
    __syncthreads();
    if (t < 56) {
        const float* w = g2w + (size_t)c*6272 + t*112;
        float s = fcb[560 + c*56 + t];
        for (int k = 0; k < 112; ++k) s += w[k]*sb[k];
        sa[t] = 1.f/(1.f+expf(-s));
    }
    __syncthreads();
    if (t < 28) {
        const float* w = g3w + (size_t)c*1568 + t*56;
        float s = fcb[840 + c*28 + t];
        for (int k = 0; k < 56; ++k) s += w[k]*sa[k];
        sb[t] = 1.f/(1.f+expf(-s));
    }
    __syncthreads();
    if (t < 14) {
        const float* w = g4w + (size_t)c*392 + t*28;
        float s = fcb[980 + c*14 + t];
        for (int k = 0; k < 28; ++k) s += w[k]*sb[k];
        sa[t] = 1.f/(1.f+expf(-s));
    }
    __syncthreads();
    if (t == 0) {
        float s = fcb[1120 + c];
        for (int p = 0; p < 14; ++p) s += sa[p]*fcb[1050 + c*14 + p];
        out[b*C_ + c] = s;
    }
}

// K7: convs + (on blockIdx.x==0) pooled + hypernet fc biases.
__global__ void k_conv(const float* __restrict__ cm,
                       const float* __restrict__ w1, const float* __restrict__ bb1,
                       const float* __restrict__ w2, const float* __restrict__ bb2,
                       const float* __restrict__ w3, const float* __restrict__ bb3,
                       const float* __restrict__ w4, const float* __restrict__ bb4,
                       float* __restrict__ o1, float* __restrict__ o2,
                       float* __restrict__ o3, float* __restrict__ o4,
                       const float* __restrict__ w1b, const float* __restrict__ b1b,
                       const float* __restrict__ w2b, const float* __restrict__ b2b,
                       const float* __restrict__ w3b, const float* __restrict__ b3b,
                       const float* __restrict__ w4b, const float* __restrict__ b4b,
                       const float* __restrict__ w5w, const float* __restrict__ b5w,
                       const float* __restrict__ w5b, const float* __restrict__ b5b,
                       float* __restrict__ fcb) {
    __shared__ float im[112*108];
    __shared__ float sp[112];
    int c = blockIdx.y;
    int t = threadIdx.x;
    for (int i = t; i < 112*108; i += 256) im[i] = 0.f;
    __syncthreads();
    const float* cmc = cm + c*5488;
    for (int i = t; i < 112*49; i += 256) {
        int ch = i / 49, yx = i - ch*49;
        int y = yx / 7, x = yx - y*7;
        im[ch*108 + (y+1)*12 + (x+1)] = cmc[i];
    }
    __syncthreads();

    int oy  = blockIdx.x*64 + (t >> 2);
    int chq = t & 3;
    if (oy < 4760) {
        int o_comb = oy / 7, y = oy - o_comb*7;
        const float* w; const float* bias; float* outp; int o;
        if      (o_comb < 512) { w=w1; bias=bb1; outp=o1 + (size_t)c*512*49; o=o_comb; }
        else if (o_comb < 640) { w=w2; bias=bb2; outp=o2 + (size_t)c*128*49; o=o_comb-512; }
        else if (o_comb < 672) { w=w3; bias=bb3; outp=o3 + (size_t)c*32*49;  o=o_comb-640; }
        else                   { w=w4; bias=bb4; outp=o4 + (size_t)c*8*49;   o=o_comb-672; }

        float ac0=0,ac1=0,ac2=0,ac3=0,ac4=0,ac5=0,ac6=0;
        const float* wbase = w + ((size_t)o*112 + chq*28)*9;
        const float* imc   = im + (chq*28)*108 + y*12;
#pragma unroll 2
        for (int ch = 0; ch < 28; ++ch) {
            const float* wk = wbase + ch*9;
            const float* ii = imc + ch*108;
            float w0=wk[0],w1_=wk[1],w2_=wk[2],w3_=wk[3],w4_=wk[4],w5_=wk[5],w6_=wk[6],w7_=wk[7],w8_=wk[8];
#pragma unroll
            for (int ky = 0; ky < 3; ++ky) {
                const float* row = ii + ky*12;
                float4 ra = *(const float4*)(row);
                float4 rb = *(const float4*)(row + 4);
                float  rc = row[8];
                float r0=ra.x,r1=ra.y,r2=ra.z,r3=ra.w,r4=rb.x,r5=rb.y,r6=rb.z,r7=rb.w,r8=rc;
                float wk0 = (ky==0)?w0:((ky==1)?w3_:w6_);
                float wk1 = (ky==0)?w1_:((ky==1)?w4_:w7_);
                float wk2 = (ky==0)?w2_:((ky==1)?w5_:w8_);
                ac0 += r0*wk0 + r1*wk1 + r2*wk2;
                ac1 += r1*wk0 + r2*wk1 + r3*wk2;
                ac2 += r2*wk0 + r3*wk1 + r4*wk2;
                ac3 += r3*wk0 + r4*wk1 + r5*wk2;
                ac4 += r4*wk0 + r5*wk1 + r6*wk2;
                ac5 += r5*wk0 + r6*wk1 + r7*wk2;
                ac6 += r6*wk0 + r7*wk1 + r8*wk2;
            }
        }
        ac0 += __shfl_xor(ac0,1,64); ac0 += __shfl_xor(ac0,2,64);
        ac1 += __shfl_xor(ac1,1,64); ac1 += __shfl_xor(ac1,2,64);
        ac2 += __shfl_xor(ac2,1,64); ac2 += __shfl_xor(ac2,2,64);
        ac3 += __shfl_xor(ac3,1,64); ac3 += __shfl_xor(ac3,2,64);
        ac4 += __shfl_xor(ac4,1,64); ac4 += __shfl_xor(ac4,2,64);
        ac5 += __shfl_xor(ac5,1,64); ac5 += __shfl_xor(ac5,2,64);
        ac6 += __shfl_xor(ac6,1,64); ac6 += __shfl_xor(ac6,2,64);
        if (chq == 0) {
            float bo = bias[o];
            float* dst = outp + o*49 + y*7;
            dst[0]=ac0+bo; dst[1]=ac1+bo; dst[2]=ac2+bo; dst[3]=ac3+bo;
            dst[4]=ac4+bo; dst[5]=ac5+bo; dst[6]=ac6+bo;
        }
    }

    if (blockIdx.x == 0) {
        if (t < 112) {
            const float* p = im + t*108;
            float s = 0.f;
            for (int k = 0; k < 108; ++k) s += p[k];
            sp[t] = s * (1.f/49.f);
        }
        __syncthreads();
        if (t < 225) {
            int rel = t;
            const float* w; const float* bb; int nout; int base;
            if      (rel < 112) {            w=w1b; bb=b1b; nout=112; base=0; }
            else if (rel < 168) { rel-=112;  w=w2b; bb=b2b; nout=56;  base=560; }
            else if (rel < 196) { rel-=168;  w=w3b; bb=b3b; nout=28;  base=840; }
            else if (rel < 210) { rel-=196;  w=w4b; bb=b4b; nout=14;  base=980; }
            else if (rel < 224) { rel-=210;  w=w5w; bb=b5w; nout=14;  base=1050; }
            else                { rel-=224;  w=w5b; bb=b5b; nout=1;   base=1120; }
            float s = bb[rel];
            const float* wr = w + rel*112;
            for (int i = 0; i < 112; ++i) s += sp[i]*wr[i];
            fcb[base + c*nout + rel] = s;
        }
    }
}

extern "C" void kernel_launch(void* const* d_in, const int* in_sizes, int n_in,
                              void* d_out, int out_size, void* d_ws, size_t ws_size,
                              hipStream_t stream) {
    (void)in_sizes; (void)n_in; (void)out_size; (void)ws_size;
    const float* tex   = (const float*)d_in[0];
    const float* fp    = (const float*)d_in[1];
    const float* eot   = (const float*)d_in[2];
    const float* fcond = (const float*)d_in[3];
    const float* qw    = (const float*)d_in[4];
    const float* qb    = (const float*)d_in[5];
    const float* cw    = (const float*)d_in[6];
    const float* cb    = (const float*)d_in[7];
    const float* w1c   = (const float*)d_in[8];  const float* b1c = (const float*)d_in[9];
    const float* w2c   = (const float*)d_in[10]; const float* b2c = (const float*)d_in[11];
    const float* w3c   = (const float*)d_in[12]; const float* b3c = (const float*)d_in[13];
    const float* w4c   = (const float*)d_in[14]; const float* b4c = (const float*)d_in[15];
    const float* f1bw  = (const float*)d_in[16]; const float* f1bb = (const float*)d_in[17];
    const float* f2bw  = (const float*)d_in[18]; const float* f2bb = (const float*)d_in[19];
    const float* f3bw  = (const float*)d_in[20]; const float* f3bb = (const float*)d_in[21];
    const float* f4bw  = (const float*)d_in[22]; const float* f4bb = (const float*)d_in[23];
    const float* f5ww  = (const float*)d_in[24]; const float* f5wb = (const float*)d_in[25];
    const float* f5bw  = (const float*)d_in[26]; const float* f5bb = (const float*)d_in[27];
    float* out = (float*)d_out;

    float* ws     = (float*)d_ws;
    float* Qb     = ws;                          // 81920
    float* part   = Qb + 81920;                  // 16*160*512 = 1310720
    float* msv    = part + 1310720;              // 16*160*2 = 5120 (8B-aligned)
    float* fusedb = msv + 5120;                  // 81920
    float* cm     = fusedb + 81920;              // 27440
    float* g1w    = cm + 27440;                  // 125440
    float* g2w    = g1w + 125440;                // 31360
    float* g3w    = g2w + 31360;                 // 7840
    float* g4w    = g3w + 7840;                  // 1960
    float* fcb    = g4w + 1960;                  // 1125
    float* fn     = fcb + 1125;                  // 2560
    float* swl    = fn + 2560;                   // 12320

    k_setup<<<1373, 256, 0, stream>>>(fcond, cw, cb, cm, fn, out + B_*C_);
    k_sim<<<77, 256, 0, stream>>>(fp, fn, swl);
    k_Q<<<dim3(2, B_), 256, 0, stream>>>(fp, swl, Qb);
    k_conv<<<dim3(75, C_), 256, 0, stream>>>(cm, w1c, b1c, w2c, b2c, w3c, b3c, w4c, b4c,
                                             g1w, g2w, g3w, g4w,
                                             f1bw, f1bb, f2bw, f2bb, f3bw, f3bb,
                                             f4bw, f4bb, f5ww, f5wb, f5bw, f5bb, fcb);
    k_attn2<<<dim3(NBA_, B_), 256, 0, stream>>>(tex, Qb, part, (float2*)msv);
    k_reduce<<<(B_*C_*D_)/256, 256, 0, stream>>>(part, (const float2*)msv, eot, fusedb);
    k_fq_target<<<B_*C_, 256, 0, stream>>>(fusedb, qw, qb,
                                           g1w, g2w, g3w, g4w, fcb, out);
}

// Round 14
// 116.435 us; speedup vs baseline: 2.6907x; 2.6907x over previous
//
#include <hip/hip_runtime.h>
#include <hip/hip_bf16.h>
#include <math.h>

#define B_   32
#define J_   1182      // V*P = 6*197
#define D_   512
#define L_   77
#define C_   5
#define JC_  64        // j-chunk for ftf
#define NCH_ 19        // ceil(1182/64)
#define NPW_ 37        // pw chunks of 32 rows

__device__ __forceinline__ float dot4(float4 a, float4 b) {
    return a.x*b.x + a.y*b.y + a.z*b.z + a.w*b.w;
}

__device__ __forceinline__ float wave_sum(float v) {
#pragma unroll
    for (int off = 32; off > 0; off >>= 1) v += __shfl_xor(v, off, 64);
    return v;
}

__device__ __forceinline__ float wave_max(float v) {
#pragma unroll
    for (int off = 32; off > 0; off >>= 1) v = fmaxf(v, __shfl_xor(v, off, 64));
    return v;
}

// K1: blocks 0..1371: cond_maps (o-major); block 1372: fn normalize + loss_dis
__global__ void k_setup(const float* __restrict__ fc, const float* __restrict__ cw,
                        const float* __restrict__ cb, float* __restrict__ cm,
                        float* __restrict__ fn, float* __restrict__ loss_out) {
    __shared__ float sfc[C_*D_];
    int t = threadIdx.x;
    for (int i = t; i < C_*D_; i += 256) sfc[i] = fc[i];
    __syncthreads();
    int wave = t >> 6, lane = t & 63;

    if (blockIdx.x == 1372) {
        for (int c = wave; c < C_; c += 4) {
            float ss = 0.f;
            for (int d = lane; d < D_; d += 64) { float v = sfc[c*D_+d]; ss += v*v; }
            ss = wave_sum(ss);
            float inv = 1.f / fmaxf(sqrtf(ss), 1e-12f);
            for (int d = lane; d < D_; d += 64) sfc[c*D_+d] *= inv;
        }
        __syncthreads();
        for (int i = t; i < C_*D_; i += 256) fn[i] = sfc[i];
        if (wave == 0) {
            float acc = 0.f;
            for (int i = 0; i < C_; ++i)
                for (int j = i+1; j < C_; ++j) {
                    float p = 0.f;
                    for (int d = lane; d < D_; d += 64) p += sfc[i*D_+d]*sfc[j*D_+d];
                    p = wave_sum(p);
                    acc += fmaxf(p, 0.f);
                }
            if (lane == 0) *loss_out = acc * (1.f/10.f);
        }
        return;
    }

    int o = blockIdx.x*4 + wave;         // < 5488
    const float4* w4 = (const float4*)(cw + (size_t)o*D_);
    float4 wa = w4[lane], wb = w4[lane+64];
    float bias = cb[o];
    float keep = 0.f;
#pragma unroll
    for (int c = 0; c < C_; ++c) {
        const float4* f4 = (const float4*)(sfc + c*D_);
        float s = dot4(wa, f4[lane]) + dot4(wb, f4[lane+64]);
        s = wave_sum(s);
        if (lane == c) keep = s;
    }
    if (lane < C_) cm[lane*5488 + o] = keep + bias;
}

// K2: 8 threads per (b,l) prompt row, 3-level shuffle reduce.
__global__ void k_sim(const float* __restrict__ fp, const float* __restrict__ fn,
                      float* __restrict__ swl) {
    int t = threadIdx.x;                 // 256 -> 32 rows/block
    int row = t >> 3, seg = t & 7;
    int bl = blockIdx.x*32 + row;        // grid 77 -> exactly 2464 rows
    int b = bl / L_, l = bl - b*L_;
    const float4* p4 = ((const float4*)(fp + (size_t)bl*D_)) + seg*16;
    const float4* f4 = ((const float4*)fn) + seg*16;
    float ss=0.f, s0=0.f, s1=0.f, s2=0.f, s3=0.f, s4=0.f;
#pragma unroll 4
    for (int k = 0; k < 16; ++k) {
        float4 v = p4[k];
        ss += dot4(v, v);
        s0 += dot4(v, f4[k]);
        s1 += dot4(v, f4[128+k]);
        s2 += dot4(v, f4[256+k]);
        s3 += dot4(v, f4[384+k]);
        s4 += dot4(v, f4[512+k]);
    }
#pragma unroll
    for (int off = 1; off < 8; off <<= 1) {
        ss += __shfl_xor(ss,off,64);
        s0 += __shfl_xor(s0,off,64); s1 += __shfl_xor(s1,off,64);
        s2 += __shfl_xor(s2,off,64); s3 += __shfl_xor(s3,off,64);
        s4 += __shfl_xor(s4,off,64);
    }
    if (seg == 0) {
        float inv = 1.f / fmaxf(sqrtf(ss), 1e-12f);
        float inv2 = inv*inv;
        swl[((size_t)(b*C_+0))*L_ + l] = s0*inv2;
        swl[((size_t)(b*C_+1))*L_ + l] = s1*inv2;
        swl[((size_t)(b*C_+2))*L_ + l] = s2*inv2;
        swl[((size_t)(b*C_+3))*L_ + l] = s3*inv2;
        swl[((size_t)(b*C_+4))*L_ + l] = s4*inv2;
    }
}

// K3 (MERGED): blocks 0..374 = conv (+hyper biases on bx==0); 375..438 = Q GEMV.
// conv and Q are independent (conv needs cm; Q needs swl) -> run concurrently.
__global__ void k_convQ(const float* __restrict__ cm,
                        const float* __restrict__ w1, const float* __restrict__ bb1,
                        const float* __restrict__ w2, const float* __restrict__ bb2,
                        const float* __restrict__ w3, const float* __restrict__ bb3,
                        const float* __restrict__ w4, const float* __restrict__ bb4,
                        float* __restrict__ o1, float* __restrict__ o2,
                        float* __restrict__ o3, float* __restrict__ o4,
                        const float* __restrict__ w1b, const float* __restrict__ b1b,
                        const float* __restrict__ w2b, const float* __restrict__ b2b,
                        const float* __restrict__ w3b, const float* __restrict__ b3b,
                        const float* __restrict__ w4b, const float* __restrict__ b4b,
                        const float* __restrict__ w5w, const float* __restrict__ b5w,
                        const float* __restrict__ w5b, const float* __restrict__ b5b,
                        float* __restrict__ fcb,
                        const float* __restrict__ fp, const float* __restrict__ swl,
                        float* __restrict__ Q) {
    __shared__ float im[112*108];
    __shared__ float sp[112];
    __shared__ float sw[C_][80];
    int bid = blockIdx.x;
    int t = threadIdx.x;

    if (bid >= 375) {
        // ---- Q part ----
        int p = bid - 375;               // < 64
        int b = p >> 1;
        int d = (p & 1)*256 + t;
        for (int i = t; i < C_*L_; i += 256) { int c = i/L_, l = i - c*L_; sw[c][l] = swl[((size_t)(b*C_+c))*L_ + l]; }
        __syncthreads();
        float a0=0.f, a1=0.f, a2=0.f, a3=0.f, a4=0.f;
        const float* f = fp + (size_t)b*L_*D_ + d;
        for (int l = 0; l < L_; ++l) {
            float v = f[(size_t)l*D_];
            a0 += sw[0][l]*v; a1 += sw[1][l]*v; a2 += sw[2][l]*v;
            a3 += sw[3][l]*v; a4 += sw[4][l]*v;
        }
        Q[(size_t)(b*C_+0)*D_ + d] = a0;
        Q[(size_t)(b*C_+1)*D_ + d] = a1;
        Q[(size_t)(b*C_+2)*D_ + d] = a2;
        Q[(size_t)(b*C_+3)*D_ + d] = a3;
        Q[(size_t)(b*C_+4)*D_ + d] = a4;
        return;
    }

    // ---- conv part ----
    int c  = bid / 75;
    int bx = bid - c*75;
    for (int i = t; i < 112*108; i += 256) im[i] = 0.f;
    __syncthreads();
    const float* cmc = cm + c*5488;
    for (int i = t; i < 112*49; i += 256) {
        int ch = i / 49, yx = i - ch*49;
        int y = yx / 7, x = yx - y*7;
        im[ch*108 + (y+1)*12 + (x+1)] = cmc[i];
    }
    __syncthreads();

    int oy  = bx*64 + (t >> 2);
    int chq = t & 3;
    if (oy < 4760) {
        int o_comb = oy / 7, y = oy - o_comb*7;
        const float* w; const float* bias; float* outp; int o;
        if      (o_comb < 512) { w=w1; bias=bb1; outp=o1 + (size_t)c*512*49; o=o_comb; }
        else if (o_comb < 640) { w=w2; bias=bb2; outp=o2 + (size_t)c*128*49; o=o_comb-512; }
        else if (o_comb < 672) { w=w3; bias=bb3; outp=o3 + (size_t)c*32*49;  o=o_comb-640; }
        else                   { w=w4; bias=bb4; outp=o4 + (size_t)c*8*49;   o=o_comb-672; }

        float ac0=0,ac1=0,ac2=0,ac3=0,ac4=0,ac5=0,ac6=0;
        const float* wbase = w + ((size_t)o*112 + chq*28)*9;
        const float* imc   = im + (chq*28)*108 + y*12;
#pragma unroll 2
        for (int ch = 0; ch < 28; ++ch) {
            const float* wk = wbase + ch*9;
            const float* ii = imc + ch*108;
            float w0=wk[0],w1_=wk[1],w2_=wk[2],w3_=wk[3],w4_=wk[4],w5_=wk[5],w6_=wk[6],w7_=wk[7],w8_=wk[8];
#pragma unroll
            for (int ky = 0; ky < 3; ++ky) {
                const float* row = ii + ky*12;
                float4 ra = *(const float4*)(row);
                float4 rb = *(const float4*)(row + 4);
                float  rc = row[8];
                float r0=ra.x,r1=ra.y,r2=ra.z,r3=ra.w,r4=rb.x,r5=rb.y,r6=rb.z,r7=rb.w,r8=rc;
                float wk0 = (ky==0)?w0:((ky==1)?w3_:w6_);
                float wk1 = (ky==0)?w1_:((ky==1)?w4_:w7_);
                float wk2 = (ky==0)?w2_:((ky==1)?w5_:w8_);
                ac0 += r0*wk0 + r1*wk1 + r2*wk2;
                ac1 += r1*wk0 + r2*wk1 + r3*wk2;
                ac2 += r2*wk0 + r3*wk1 + r4*wk2;
                ac3 += r3*wk0 + r4*wk1 + r5*wk2;
                ac4 += r4*wk0 + r5*wk1 + r6*wk2;
                ac5 += r5*wk0 + r6*wk1 + r7*wk2;
                ac6 += r6*wk0 + r7*wk1 + r8*wk2;
            }
        }
        ac0 += __shfl_xor(ac0,1,64); ac0 += __shfl_xor(ac0,2,64);
        ac1 += __shfl_xor(ac1,1,64); ac1 += __shfl_xor(ac1,2,64);
        ac2 += __shfl_xor(ac2,1,64); ac2 += __shfl_xor(ac2,2,64);
        ac3 += __shfl_xor(ac3,1,64); ac3 += __shfl_xor(ac3,2,64);
        ac4 += __shfl_xor(ac4,1,64); ac4 += __shfl_xor(ac4,2,64);
        ac5 += __shfl_xor(ac5,1,64); ac5 += __shfl_xor(ac5,2,64);
        ac6 += __shfl_xor(ac6,1,64); ac6 += __shfl_xor(ac6,2,64);
        if (chq == 0) {
            float bo = bias[o];
            float* dst = outp + o*49 + y*7;
            dst[0]=ac0+bo; dst[1]=ac1+bo; dst[2]=ac2+bo; dst[3]=ac3+bo;
            dst[4]=ac4+bo; dst[5]=ac5+bo; dst[6]=ac6+bo;
        }
    }

    if (bx == 0) {
        if (t < 112) {
            const float* p = im + t*108;
            float s = 0.f;
            for (int k = 0; k < 108; ++k) s += p[k];
            sp[t] = s * (1.f/49.f);
        }
        __syncthreads();
        if (t < 225) {
            int rel = t;
            const float* w; const float* bb; int nout; int base;
            if      (rel < 112) {            w=w1b; bb=b1b; nout=112; base=0; }
            else if (rel < 168) { rel-=112;  w=w2b; bb=b2b; nout=56;  base=560; }
            else if (rel < 196) { rel-=168;  w=w3b; bb=b3b; nout=28;  base=840; }
            else if (rel < 210) { rel-=196;  w=w4b; bb=b4b; nout=14;  base=980; }
            else if (rel < 224) { rel-=210;  w=w5w; bb=b5w; nout=14;  base=1050; }
            else                { rel-=224;  w=w5b; bb=b5b; nout=1;   base=1120; }
            float s = bb[rel];
            const float* wr = w + rel*112;
            for (int i = 0; i < 112; ++i) s += sp[i]*wr[i];
            fcb[base + c*nout + rel] = s;
        }
    }
}

// K4: pw scores [tex pass #1] + per-chunk partial softmax stats.
// grid (NPW_, B_), 256 thr = 32 rows x 8 segs. NO early return (barrier below).
__global__ void k_pw(const float* __restrict__ tex, const float* __restrict__ Q,
                     float* __restrict__ pw, float2* __restrict__ pstat) {
    __shared__ float4 qs[C_*128];        // 10240 B, swizzled (c*16+k)*8+seg
    __shared__ float sraw[C_][32];
    int bx = blockIdx.x, b = blockIdx.y, t = threadIdx.x;
    {
        const float4* q4 = (const float4*)(Q + (size_t)b*C_*D_);
        for (int i = t; i < C_*128; i += 256) {
            int c = i >> 7, f = i & 127;
            qs[(c*16 + (f & 15))*8 + (f >> 4)] = q4[i];
        }
    }
    __syncthreads();
    int row = t >> 3, seg = t & 7;
    int j = bx*32 + row;
    bool valid = (j < J_);
    int jc = valid ? j : (J_-1);
    const float4* tp = (const float4*)(tex + ((size_t)(b*J_ + jc))*D_ + seg*64);
    float ss=0.f, s0=0.f, s1=0.f, s2=0.f, s3=0.f, s4=0.f;
#pragma unroll 4
    for (int k = 0; k < 16; ++k) {
        float4 v = tp[k];
        int base = k*8 + seg;
        ss += dot4(v, v);
        s0 += dot4(v, qs[base]);
        s1 += dot4(v, qs[128 + base]);
        s2 += dot4(v, qs[256 + base]);
        s3 += dot4(v, qs[384 + base]);
        s4 += dot4(v, qs[512 + base]);
    }
#pragma unroll
    for (int off = 1; off < 8; off <<= 1) {
        ss += __shfl_xor(ss,off,64);
        s0 += __shfl_xor(s0,off,64); s1 += __shfl_xor(s1,off,64);
        s2 += __shfl_xor(s2,off,64); s3 += __shfl_xor(s3,off,64);
        s4 += __shfl_xor(s4,off,64);
    }
    if (seg == 0) {
        float inv = 1.f / fmaxf(sqrtf(ss), 1e-12f);
        float r0 = s0*inv, r1 = s1*inv, r2 = s2*inv, r3 = s3*inv, r4 = s4*inv;
        if (valid) {
            pw[((size_t)(b*C_+0))*J_ + j] = r0;
            pw[((size_t)(b*C_+1))*J_ + j] = r1;
            pw[((size_t)(b*C_+2))*J_ + j] = r2;
            pw[((size_t)(b*C_+3))*J_ + j] = r3;
            pw[((size_t)(b*C_+4))*J_ + j] = r4;
            sraw[0][row]=r0; sraw[1][row]=r1; sraw[2][row]=r2; sraw[3][row]=r3; sraw[4][row]=r4;
        } else {
            sraw[0][row]=-1e30f; sraw[1][row]=-1e30f; sraw[2][row]=-1e30f;
            sraw[3][row]=-1e30f; sraw[4][row]=-1e30f;
        }
    }
    __syncthreads();
    if (t < C_*32) {
        int c = t >> 5, r2 = t & 31;
        float v = sraw[c][r2];
        float m = v;
#pragma unroll
        for (int off = 1; off < 32; off <<= 1) m = fmaxf(m, __shfl_xor(m,off,32));
        float e = (v > -1e29f) ? expf(v - m) : 0.f;
#pragma unroll
        for (int off = 1; off < 32; off <<= 1) e += __shfl_xor(e,off,32);
        if (r2 == 0) pstat[(size_t)(bx*B_ + b)*C_ + c] = make_float2(m, e);
    }
}

// K5: ftf partials [tex pass #2]; pre-phase combines 37 partial stats -> (m, 1/denom).
__global__ void k_ftf(const float* __restrict__ tex, const float* __restrict__ pwraw,
                      const float2* __restrict__ pstat, float* __restrict__ part) {
    __shared__ float sw[C_][JC_];
    __shared__ float2 sL[C_];
    int chunk = blockIdx.x, b = blockIdx.y;
    int t = threadIdx.x;                 // 512
    int wave = t >> 6, lane = t & 63;
    if (wave < C_) {
        float2 pv = (lane < NPW_) ? pstat[(size_t)(lane*B_ + b)*C_ + wave]
                                  : make_float2(-1e30f, 0.f);
        float m = wave_max(pv.x);
        float contrib = (lane < NPW_) ? pv.y * expf(pv.x - m) : 0.f;
        float denom = wave_sum(contrib);
        if (lane == 0) sL[wave] = make_float2(m, 1.f/denom);
    }
    __syncthreads();
    int j0 = chunk*JC_;
    int jn = min(JC_, J_ - j0);
    if (t < C_*JC_) {
        int c = t >> 6, jj = t & 63;
        float2 ms = sL[c];
        sw[c][jj] = (jj < jn)
            ? expf(pwraw[((size_t)(b*C_+c))*J_ + j0 + jj] - ms.x) * ms.y
            : 0.f;
    }
    __syncthreads();
    float acc0=0.f, acc1=0.f, acc2=0.f, acc3=0.f, acc4=0.f;
    const float* tp = tex + ((size_t)b*J_ + j0)*D_ + t;
    for (int jj = 0; jj < jn; ++jj) {
        float v = tp[(size_t)jj*D_];
        acc0 += v*sw[0][jj]; acc1 += v*sw[1][jj]; acc2 += v*sw[2][jj];
        acc3 += v*sw[3][jj]; acc4 += v*sw[4][jj];
    }
    size_t base = (((size_t)chunk*B_ + b)*C_)*D_ + t;
    part[base               ] = acc0;
    part[base +   (size_t)D_] = acc1;
    part[base + 2*(size_t)D_] = acc2;
    part[base + 3*(size_t)D_] = acc3;
    part[base + 4*(size_t)D_] = acc4;
}

// K6: fused chunk-reduce + eot + fq + TargetNet per (b,c) block.
__global__ void k_fq_target(const float* __restrict__ part, const float* __restrict__ eot,
                            const float* __restrict__ qw, const float* __restrict__ qb,
                            const float* __restrict__ g1w, const float* __restrict__ g2w,
                            const float* __restrict__ g3w, const float* __restrict__ g4w,
                            const float* __restrict__ fcb, float* __restrict__ out) {
    int bc = blockIdx.x; int b = bc / C_; int c = bc - b*C_;
    __shared__ float sf[D_];
    __shared__ float sa[224], sb[112];
    int t = threadIdx.x;                 // 256

    float s0 = 0.f, s1 = 0.f;
    for (int ch = 0; ch < NCH_; ++ch) {
        const float* p = part + ((size_t)ch*(B_*C_) + bc)*D_;
        s0 += p[t]; s1 += p[t+256];
    }
    sf[t]     = s0 * eot[b*D_ + t];
    sf[t+256] = s1 * eot[b*D_ + t + 256];
    __syncthreads();

    if (t < 224) {
        const float4* w4 = (const float4*)(qw + (size_t)t*D_);
        const float4* s4 = (const float4*)sf;
        float acc = 0.f;
#pragma unroll 4
        for (int i = 0; i < 128; ++i) acc += dot4(s4[i], w4[i]);
        sa[t] = acc + qb[t];
    }
    __syncthreads();

    if (t < 112) {
        const float* w = g1w + (size_t)c*25088 + t*224;
        float s = fcb[c*112 + t];
        for (int k = 0; k < 224; ++k) s += w[k]*sa[k];
        sb[t] = 1.f/(1.f+expf(-s));
    }
    __syncthreads();
    if (t < 56) {
        const float* w = g2w + (size_t)c*6272 + t*112;
        float s = fcb[560 + c*56 + t];
        for (int k = 0; k < 112; ++k) s += w[k]*sb[k];
        sa[t] = 1.f/(1.f+expf(-s));
    }
    __syncthreads();
    if (t < 28) {
        const float* w = g3w + (size_t)c*1568 + t*56;
        float s = fcb[840 + c*28 + t];
        for (int k = 0; k < 56; ++k) s += w[k]*sa[k];
        sb[t] = 1.f/(1.f+expf(-s));
    }
    __syncthreads();
    if (t < 14) {
        const float* w = g4w + (size_t)c*392 + t*28;
        float s = fcb[980 + c*14 + t];
        for (int k = 0; k < 28; ++k) s += w[k]*sb[k];
        sa[t] = 1.f/(1.f+expf(-s));
    }
    __syncthreads();
    if (t == 0) {
        float s = fcb[1120 + c];
        for (int p = 0; p < 14; ++p) s += sa[p]*fcb[1050 + c*14 + p];
        out[b*C_ + c] = s;
    }
}

extern "C" void kernel_launch(void* const* d_in, const int* in_sizes, int n_in,
                              void* d_out, int out_size, void* d_ws, size_t ws_size,
                              hipStream_t stream) {
    (void)in_sizes; (void)n_in; (void)out_size; (void)ws_size;
    const float* tex   = (const float*)d_in[0];
    const float* fp    = (const float*)d_in[1];
    const float* eot   = (const float*)d_in[2];
    const float* fcond = (const float*)d_in[3];
    const float* qw    = (const float*)d_in[4];
    const float* qb    = (const float*)d_in[5];
    const float* cw    = (const float*)d_in[6];
    const float* cb    = (const float*)d_in[7];
    const float* w1c   = (const float*)d_in[8];  const float* b1c = (const float*)d_in[9];
    const float* w2c   = (const float*)d_in[10]; const float* b2c = (const float*)d_in[11];
    const float* w3c   = (const float*)d_in[12]; const float* b3c = (const float*)d_in[13];
    const float* w4c   = (const float*)d_in[14]; const float* b4c = (const float*)d_in[15];
    const float* f1bw  = (const float*)d_in[16]; const float* f1bb = (const float*)d_in[17];
    const float* f2bw  = (const float*)d_in[18]; const float* f2bb = (const float*)d_in[19];
    const float* f3bw  = (const float*)d_in[20]; const float* f3bb = (const float*)d_in[21];
    const float* f4bw  = (const float*)d_in[22]; const float* f4bb = (const float*)d_in[23];
    const float* f5ww  = (const float*)d_in[24]; const float* f5wb = (const float*)d_in[25];
    const float* f5bw  = (const float*)d_in[26]; const float* f5bb = (const float*)d_in[27];
    float* out = (float*)d_out;

    float* ws     = (float*)d_ws;
    float* Qb     = ws;                          // 81920
    float* pw     = Qb + 81920;                  // 189120
    float* part   = pw + 189120;                 // 19*81920 = 1556480
    float* pstat  = part + 1556480;              // 37*32*5*2 = 11840 (8B-aligned)
    float* cm     = pstat + 11840;               // 27440
    float* g1w    = cm + 27440;                  // 125440
    float* g2w    = g1w + 125440;                // 31360
    float* g3w    = g2w + 31360;                 // 7840
    float* g4w    = g3w + 7840;                  // 1960
    float* fcb    = g4w + 1960;                  // 1125
    float* fn     = fcb + 1125;                  // 2560
    float* swl    = fn + 2560;                   // 12320

    k_setup<<<1373, 256, 0, stream>>>(fcond, cw, cb, cm, fn, out + B_*C_);
    k_sim<<<77, 256, 0, stream>>>(fp, fn, swl);
    k_convQ<<<439, 256, 0, stream>>>(cm, w1c, b1c, w2c, b2c, w3c, b3c, w4c, b4c,
                                     g1w, g2w, g3w, g4w,
                                     f1bw, f1bb, f2bw, f2bb, f3bw, f3bb,
                                     f4bw, f4bb, f5ww, f5wb, f5bw, f5bb, fcb,
                                     fp, swl, Qb);
    k_pw<<<dim3(NPW_, B_), 256, 0, stream>>>(tex, Qb, pw, (float2*)pstat);
    k_ftf<<<dim3(NCH_, B_), 512, 0, stream>>>(tex, pw, (const float2*)pstat, part);
    k_fq_target<<<B_*C_, 256, 0, stream>>>(part, eot, qw, qb,
                                           g1w, g2w, g3w, g4w, fcb, out);
}

// Round 15
// 98.236 us; speedup vs baseline: 3.1892x; 1.1853x over previous
//
#include <hip/hip_runtime.h>
#include <hip/hip_bf16.h>
#include <math.h>

#define B_   32
#define J_   1182      // V*P = 6*197
#define D_   512
#define L_   77
#define C_   5
#define JC_  64        // j-chunk for ftf
#define NCH_ 19        // ceil(1182/64)
#define NPW_ 37        // pw chunks of 32 rows

__device__ __forceinline__ float dot4(float4 a, float4 b) {
    return a.x*b.x + a.y*b.y + a.z*b.z + a.w*b.w;
}

__device__ __forceinline__ float wave_sum(float v) {
#pragma unroll
    for (int off = 32; off > 0; off >>= 1) v += __shfl_xor(v, off, 64);
    return v;
}

__device__ __forceinline__ float wave_max(float v) {
#pragma unroll
    for (int off = 32; off > 0; off >>= 1) v = fmaxf(v, __shfl_xor(v, off, 64));
    return v;
}

// K1 (MERGED front-end):
//  blocks 0..1371  : cond_maps (o-major, wave per o)
//  block 1372      : loss_dis (normalize fcond in LDS, pairwise relu-cos mean)
//  blocks 1373..1449: sim — fn computed redundantly in-block into swizzled LDS
//                     (qs layout (c*16+k)*8+seg, conflict-free), then 32 rows
//                     of fp per block: norm + 5 condition dots -> swl.
__global__ void k_front(const float* __restrict__ fc, const float* __restrict__ cw,
                        const float* __restrict__ cb, float* __restrict__ cm,
                        float* __restrict__ loss_out,
                        const float* __restrict__ fp, float* __restrict__ swl) {
    __shared__ float4 smem4[640];        // 10240 B (aliased: sfc | fnq)
    float* sfc = (float*)smem4;
    int bid = blockIdx.x, t = threadIdx.x;
    int wave = t >> 6, lane = t & 63;

    if (bid < 1373) {
        for (int i = t; i < C_*D_; i += 256) sfc[i] = fc[i];
        __syncthreads();

        if (bid == 1372) {
            for (int c = wave; c < C_; c += 4) {
                float ss = 0.f;
                for (int d = lane; d < D_; d += 64) { float v = sfc[c*D_+d]; ss += v*v; }
                ss = wave_sum(ss);
                float inv = 1.f / fmaxf(sqrtf(ss), 1e-12f);
                for (int d = lane; d < D_; d += 64) sfc[c*D_+d] *= inv;
            }
            __syncthreads();
            if (wave == 0) {
                float acc = 0.f;
                for (int i = 0; i < C_; ++i)
                    for (int j = i+1; j < C_; ++j) {
                        float p = 0.f;
                        for (int d = lane; d < D_; d += 64) p += sfc[i*D_+d]*sfc[j*D_+d];
                        p = wave_sum(p);
                        acc += fmaxf(p, 0.f);
                    }
                if (lane == 0) *loss_out = acc * (1.f/10.f);
            }
            return;
        }

        int o = bid*4 + wave;            // < 5488
        const float4* w4 = (const float4*)(cw + (size_t)o*D_);
        float4 wa = w4[lane], wb = w4[lane+64];
        float bias = cb[o];
        float keep = 0.f;
#pragma unroll
        for (int c = 0; c < C_; ++c) {
            const float4* f4 = (const float4*)(sfc + c*D_);
            float s = dot4(wa, f4[lane]) + dot4(wb, f4[lane+64]);
            s = wave_sum(s);
            if (lane == c) keep = s;
        }
        if (lane < C_) cm[lane*5488 + o] = keep + bias;
        return;
    }

    // ---- sim part ----
    // fn -> swizzled LDS: fnq[(c*16+k)*8+seg]
    for (int c = wave; c < C_; c += 4) {
        const float4* f8 = (const float4*)(fc + c*D_);
        float4 v0 = f8[lane*2], v1 = f8[lane*2+1];
        float ss = dot4(v0,v0) + dot4(v1,v1);
        ss = wave_sum(ss);
        float inv = 1.f / fmaxf(sqrtf(ss), 1e-12f);
        v0.x*=inv; v0.y*=inv; v0.z*=inv; v0.w*=inv;
        v1.x*=inv; v1.y*=inv; v1.z*=inv; v1.w*=inv;
        int f0 = lane*2, f1 = lane*2+1;
        smem4[(c*16 + (f0 & 15))*8 + (f0 >> 4)] = v0;
        smem4[(c*16 + (f1 & 15))*8 + (f1 >> 4)] = v1;
    }
    __syncthreads();

    int row = t >> 3, seg = t & 7;
    int bl = (bid - 1373)*32 + row;      // < 2464 exactly
    int b = bl / L_, l = bl - b*L_;
    const float4* p4 = ((const float4*)(fp + (size_t)bl*D_)) + seg*16;
    float ss=0.f, s0=0.f, s1=0.f, s2=0.f, s3=0.f, s4=0.f;
#pragma unroll 4
    for (int k = 0; k < 16; ++k) {
        float4 v = p4[k];
        int base = k*8 + seg;
        ss += dot4(v, v);
        s0 += dot4(v, smem4[base]);
        s1 += dot4(v, smem4[128 + base]);
        s2 += dot4(v, smem4[256 + base]);
        s3 += dot4(v, smem4[384 + base]);
        s4 += dot4(v, smem4[512 + base]);
    }
#pragma unroll
    for (int off = 1; off < 8; off <<= 1) {
        ss += __shfl_xor(ss,off,64);
        s0 += __shfl_xor(s0,off,64); s1 += __shfl_xor(s1,off,64);
        s2 += __shfl_xor(s2,off,64); s3 += __shfl_xor(s3,off,64);
        s4 += __shfl_xor(s4,off,64);
    }
    if (seg == 0) {
        float inv = 1.f / fmaxf(sqrtf(ss), 1e-12f);
        float inv2 = inv*inv;
        swl[((size_t)(b*C_+0))*L_ + l] = s0*inv2;
        swl[((size_t)(b*C_+1))*L_ + l] = s1*inv2;
        swl[((size_t)(b*C_+2))*L_ + l] = s2*inv2;
        swl[((size_t)(b*C_+3))*L_ + l] = s3*inv2;
        swl[((size_t)(b*C_+4))*L_ + l] = s4*inv2;
    }
}

// K2: Q[b,c,d] = sum_l swl[b,c,l] * fp[b,l,d]   grid (2, B_), 256 thr
__global__ void k_Q(const float* __restrict__ fp, const float* __restrict__ swl,
                    float* __restrict__ Q) {
    __shared__ float sw[C_][80];
    int b = blockIdx.y;
    int t = threadIdx.x;
    for (int i = t; i < C_*L_; i += 256) { int c = i/L_, l = i - c*L_; sw[c][l] = swl[((size_t)(b*C_+c))*L_ + l]; }
    __syncthreads();
    int d = blockIdx.x*256 + t;
    float a0=0.f, a1=0.f, a2=0.f, a3=0.f, a4=0.f;
    const float* f = fp + (size_t)b*L_*D_ + d;
    for (int l = 0; l < L_; ++l) {
        float v = f[(size_t)l*D_];
        a0 += sw[0][l]*v; a1 += sw[1][l]*v; a2 += sw[2][l]*v;
        a3 += sw[3][l]*v; a4 += sw[4][l]*v;
    }
    Q[(size_t)(b*C_+0)*D_ + d] = a0;
    Q[(size_t)(b*C_+1)*D_ + d] = a1;
    Q[(size_t)(b*C_+2)*D_ + d] = a2;
    Q[(size_t)(b*C_+3)*D_ + d] = a3;
    Q[(size_t)(b*C_+4)*D_ + d] = a4;
}

// K3 (MERGED): blocks 0..374 = conv (+hyper biases on bx==0); 375..1558 = pw.
// conv (needs cm) hides under the L3-BW-bound pw tex pass (needs Qb).
// LDS aliased: conv im[12096]+sp[112] | pw qs[640 f4]+sraw[160].
__global__ void k_conv_pw(const float* __restrict__ cm,
                          const float* __restrict__ w1, const float* __restrict__ bb1,
                          const float* __restrict__ w2, const float* __restrict__ bb2,
                          const float* __restrict__ w3, const float* __restrict__ bb3,
                          const float* __restrict__ w4, const float* __restrict__ bb4,
                          float* __restrict__ o1, float* __restrict__ o2,
                          float* __restrict__ o3, float* __restrict__ o4,
                          const float* __restrict__ w1b, const float* __restrict__ b1b,
                          const float* __restrict__ w2b, const float* __restrict__ b2b,
                          const float* __restrict__ w3b, const float* __restrict__ b3b,
                          const float* __restrict__ w4b, const float* __restrict__ b4b,
                          const float* __restrict__ w5w, const float* __restrict__ b5w,
                          const float* __restrict__ w5b, const float* __restrict__ b5b,
                          float* __restrict__ fcb,
                          const float* __restrict__ tex, const float* __restrict__ Q,
                          float* __restrict__ pw, float2* __restrict__ pstat) {
    __shared__ float4 smem4[3052];       // 48832 B
    int bid = blockIdx.x;
    int t = threadIdx.x;

    if (bid >= 375) {
        // ---- pw part ----
        float4* qs = smem4;
        float* sraw = (float*)(smem4 + 640);   // [C_][32]
        int p = bid - 375;
        int bx = p % NPW_, b = p / NPW_;
        {
            const float4* q4 = (const float4*)(Q + (size_t)b*C_*D_);
            for (int i = t; i < C_*128; i += 256) {
                int c = i >> 7, f = i & 127;
                qs[(c*16 + (f & 15))*8 + (f >> 4)] = q4[i];
            }
        }
        __syncthreads();
        int row = t >> 3, seg = t & 7;
        int j = bx*32 + row;
        bool valid = (j < J_);
        int jc = valid ? j : (J_-1);
        const float4* tp = (const float4*)(tex + ((size_t)(b*J_ + jc))*D_ + seg*64);
        float ss=0.f, s0=0.f, s1=0.f, s2=0.f, s3=0.f, s4=0.f;
#pragma unroll 4
        for (int k = 0; k < 16; ++k) {
            float4 v = tp[k];
            int base = k*8 + seg;
            ss += dot4(v, v);
            s0 += dot4(v, qs[base]);
            s1 += dot4(v, qs[128 + base]);
            s2 += dot4(v, qs[256 + base]);
            s3 += dot4(v, qs[384 + base]);
            s4 += dot4(v, qs[512 + base]);
        }
#pragma unroll
        for (int off = 1; off < 8; off <<= 1) {
            ss += __shfl_xor(ss,off,64);
            s0 += __shfl_xor(s0,off,64); s1 += __shfl_xor(s1,off,64);
            s2 += __shfl_xor(s2,off,64); s3 += __shfl_xor(s3,off,64);
            s4 += __shfl_xor(s4,off,64);
        }
        if (seg == 0) {
            float inv = 1.f / fmaxf(sqrtf(ss), 1e-12f);
            float r0 = s0*inv, r1 = s1*inv, r2 = s2*inv, r3 = s3*inv, r4 = s4*inv;
            if (valid) {
                pw[((size_t)(b*C_+0))*J_ + j] = r0;
                pw[((size_t)(b*C_+1))*J_ + j] = r1;
                pw[((size_t)(b*C_+2))*J_ + j] = r2;
                pw[((size_t)(b*C_+3))*J_ + j] = r3;
                pw[((size_t)(b*C_+4))*J_ + j] = r4;
                sraw[0*32+row]=r0; sraw[1*32+row]=r1; sraw[2*32+row]=r2;
                sraw[3*32+row]=r3; sraw[4*32+row]=r4;
            } else {
                sraw[0*32+row]=-1e30f; sraw[1*32+row]=-1e30f; sraw[2*32+row]=-1e30f;
                sraw[3*32+row]=-1e30f; sraw[4*32+row]=-1e30f;
            }
        }
        __syncthreads();
        if (t < C_*32) {
            int c = t >> 5, r2 = t & 31;
            float v = sraw[c*32 + r2];
            float m = v;
#pragma unroll
            for (int off = 1; off < 32; off <<= 1) m = fmaxf(m, __shfl_xor(m,off,32));
            float e = (v > -1e29f) ? expf(v - m) : 0.f;
#pragma unroll
            for (int off = 1; off < 32; off <<= 1) e += __shfl_xor(e,off,32);
            if (r2 == 0) pstat[(size_t)(bx*B_ + b)*C_ + c] = make_float2(m, e);
        }
        return;
    }

    // ---- conv part ----
    float* im = (float*)smem4;           // 12096 floats
    float* sp = im + 12096;              // 112 floats
    int c  = bid / 75;
    int bx = bid - c*75;
    for (int i = t; i < 112*108; i += 256) im[i] = 0.f;
    __syncthreads();
    const float* cmc = cm + c*5488;
    for (int i = t; i < 112*49; i += 256) {
        int ch = i / 49, yx = i - ch*49;
        int y = yx / 7, x = yx - y*7;
        im[ch*108 + (y+1)*12 + (x+1)] = cmc[i];
    }
    __syncthreads();

    int oy  = bx*64 + (t >> 2);
    int chq = t & 3;
    if (oy < 4760) {
        int o_comb = oy / 7, y = oy - o_comb*7;
        const float* w; const float* bias; float* outp; int o;
        if      (o_comb < 512) { w=w1; bias=bb1; outp=o1 + (size_t)c*512*49; o=o_comb; }
        else if (o_comb < 640) { w=w2; bias=bb2; outp=o2 + (size_t)c*128*49; o=o_comb-512; }
        else if (o_comb < 672) { w=w3; bias=bb3; outp=o3 + (size_t)c*32*49;  o=o_comb-640; }
        else                   { w=w4; bias=bb4; outp=o4 + (size_t)c*8*49;   o=o_comb-672; }

        float ac0=0,ac1=0,ac2=0,ac3=0,ac4=0,ac5=0,ac6=0;
        const float* wbase = w + ((size_t)o*112 + chq*28)*9;
        const float* imc   = im + (chq*28)*108 + y*12;
#pragma unroll 2
        for (int ch = 0; ch < 28; ++ch) {
            const float* wk = wbase + ch*9;
            const float* ii = imc + ch*108;
            float w0=wk[0],w1_=wk[1],w2_=wk[2],w3_=wk[3],w4_=wk[4],w5_=wk[5],w6_=wk[6],w7_=wk[7],w8_=wk[8];
#pragma unroll
            for (int ky = 0; ky < 3; ++ky) {
                const float* row = ii + ky*12;
                float4 ra = *(const float4*)(row);
                float4 rb = *(const float4*)(row + 4);
                float  rc = row[8];
                float r0=ra.x,r1=ra.y,r2=ra.z,r3=ra.w,r4=rb.x,r5=rb.y,r6=rb.z,r7=rb.w,r8=rc;
                float wk0 = (ky==0)?w0:((ky==1)?w3_:w6_);
                float wk1 = (ky==0)?w1_:((ky==1)?w4_:w7_);
                float wk2 = (ky==0)?w2_:((ky==1)?w5_:w8_);
                ac0 += r0*wk0 + r1*wk1 + r2*wk2;
                ac1 += r1*wk0 + r2*wk1 + r3*wk2;
                ac2 += r2*wk0 + r3*wk1 + r4*wk2;
                ac3 += r3*wk0 + r4*wk1 + r5*wk2;
                ac4 += r4*wk0 + r5*wk1 + r6*wk2;
                ac5 += r5*wk0 + r6*wk1 + r7*wk2;
                ac6 += r6*wk0 + r7*wk1 + r8*wk2;
            }
        }
        ac0 += __shfl_xor(ac0,1,64); ac0 += __shfl_xor(ac0,2,64);
        ac1 += __shfl_xor(ac1,1,64); ac1 += __shfl_xor(ac1,2,64);
        ac2 += __shfl_xor(ac2,1,64); ac2 += __shfl_xor(ac2,2,64);
        ac3 += __shfl_xor(ac3,1,64); ac3 += __shfl_xor(ac3,2,64);
        ac4 += __shfl_xor(ac4,1,64); ac4 += __shfl_xor(ac4,2,64);
        ac5 += __shfl_xor(ac5,1,64); ac5 += __shfl_xor(ac5,2,64);
        ac6 += __shfl_xor(ac6,1,64); ac6 += __shfl_xor(ac6,2,64);
        if (chq == 0) {
            float bo = bias[o];
            float* dst = outp + o*49 + y*7;
            dst[0]=ac0+bo; dst[1]=ac1+bo; dst[2]=ac2+bo; dst[3]=ac3+bo;
            dst[4]=ac4+bo; dst[5]=ac5+bo; dst[6]=ac6+bo;
        }
    }

    if (bx == 0) {
        if (t < 112) {
            const float* p = im + t*108;
            float s = 0.f;
            for (int k = 0; k < 108; ++k) s += p[k];
            sp[t] = s * (1.f/49.f);
        }
        __syncthreads();
        if (t < 225) {
            int rel = t;
            const float* w; const float* bb; int nout; int base;
            if      (rel < 112) {            w=w1b; bb=b1b; nout=112; base=0; }
            else if (rel < 168) { rel-=112;  w=w2b; bb=b2b; nout=56;  base=560; }
            else if (rel < 196) { rel-=168;  w=w3b; bb=b3b; nout=28;  base=840; }
            else if (rel < 210) { rel-=196;  w=w4b; bb=b4b; nout=14;  base=980; }
            else if (rel < 224) { rel-=210;  w=w5w; bb=b5w; nout=14;  base=1050; }
            else                { rel-=224;  w=w5b; bb=b5b; nout=1;   base=1120; }
            float s = bb[rel];
            const float* wr = w + rel*112;
            for (int i = 0; i < 112; ++i) s += sp[i]*wr[i];
            fcb[base + c*nout + rel] = s;
        }
    }
}

// K4: ftf partials [tex pass #2]; pre-phase combines 37 partial stats -> (m, 1/denom).
__global__ void k_ftf(const float* __restrict__ tex, const float* __restrict__ pwraw,
                      const float2* __restrict__ pstat, float* __restrict__ part) {
    __shared__ float sw[C_][JC_];
    __shared__ float2 sL[C_];
    int chunk = blockIdx.x, b = blockIdx.y;
    int t = threadIdx.x;                 // 512
    int wave = t >> 6, lane = t & 63;
    if (wave < C_) {
        float2 pv = (lane < NPW_) ? pstat[(size_t)(lane*B_ + b)*C_ + wave]
                                  : make_float2(-1e30f, 0.f);
        float m = wave_max(pv.x);
        float contrib = (lane < NPW_) ? pv.y * expf(pv.x - m) : 0.f;
        float denom = wave_sum(contrib);
        if (lane == 0) sL[wave] = make_float2(m, 1.f/denom);
    }
    __syncthreads();
    int j0 = chunk*JC_;
    int jn = min(JC_, J_ - j0);
    if (t < C_*JC_) {
        int c = t >> 6, jj = t & 63;
        float2 ms = sL[c];
        sw[c][jj] = (jj < jn)
            ? expf(pwraw[((size_t)(b*C_+c))*J_ + j0 + jj] - ms.x) * ms.y
            : 0.f;
    }
    __syncthreads();
    float acc0=0.f, acc1=0.f, acc2=0.f, acc3=0.f, acc4=0.f;
    const float* tp = tex + ((size_t)b*J_ + j0)*D_ + t;
    for (int jj = 0; jj < jn; ++jj) {
        float v = tp[(size_t)jj*D_];
        acc0 += v*sw[0][jj]; acc1 += v*sw[1][jj]; acc2 += v*sw[2][jj];
        acc3 += v*sw[3][jj]; acc4 += v*sw[4][jj];
    }
    size_t base = (((size_t)chunk*B_ + b)*C_)*D_ + t;
    part[base               ] = acc0;
    part[base +   (size_t)D_] = acc1;
    part[base + 2*(size_t)D_] = acc2;
    part[base + 3*(size_t)D_] = acc3;
    part[base + 4*(size_t)D_] = acc4;
}

// K5: fused chunk-reduce + eot + fq + TargetNet per (b,c) block.
__global__ void k_fq_target(const float* __restrict__ part, const float* __restrict__ eot,
                            const float* __restrict__ qw, const float* __restrict__ qb,
                            const float* __restrict__ g1w, const float* __restrict__ g2w,
                            const float* __restrict__ g3w, const float* __restrict__ g4w,
                            const float* __restrict__ fcb, float* __restrict__ out) {
    int bc = blockIdx.x; int b = bc / C_; int c = bc - b*C_;
    __shared__ float sf[D_];
    __shared__ float sa[224], sb[112];
    int t = threadIdx.x;                 // 256

    float s0 = 0.f, s1 = 0.f;
    for (int ch = 0; ch < NCH_; ++ch) {
        const float* p = part + ((size_t)ch*(B_*C_) + bc)*D_;
        s0 += p[t]; s1 += p[t+256];
    }
    sf[t]     = s0 * eot[b*D_ + t];
    sf[t+256] = s1 * eot[b*D_ + t + 256];
    __syncthreads();

    if (t < 224) {
        const float4* w4 = (const float4*)(qw + (size_t)t*D_);
        const float4* s4 = (const float4*)sf;
        float acc = 0.f;
#pragma unroll 4
        for (int i = 0; i < 128; ++i) acc += dot4(s4[i], w4[i]);
        sa[t] = acc + qb[t];
    }
    __syncthreads();

    if (t < 112) {
        const float* w = g1w + (size_t)c*25088 + t*224;
        float s = fcb[c*112 + t];
        for (int k = 0; k < 224; ++k) s += w[k]*sa[k];
        sb[t] = 1.f/(1.f+expf(-s));
    }
    __syncthreads();
    if (t < 56) {
        const float* w = g2w + (size_t)c*6272 + t*112;
        float s = fcb[560 + c*56 + t];
        for (int k = 0; k < 112; ++k) s += w[k]*sb[k];
        sa[t] = 1.f/(1.f+expf(-s));
    }
    __syncthreads();
    if (t < 28) {
        const float* w = g3w + (size_t)c*1568 + t*56;
        float s = fcb[840 + c*28 + t];
        for (int k = 0; k < 56; ++k) s += w[k]*sa[k];
        sb[t] = 1.f/(1.f+expf(-s));
    }
    __syncthreads();
    if (t < 14) {
        const float* w = g4w + (size_t)c*392 + t*28;
        float s = fcb[980 + c*14 + t];
        for (int k = 0; k < 28; ++k) s += w[k]*sb[k];
        sa[t] = 1.f/(1.f+expf(-s));
    }
    __syncthreads();
    if (t == 0) {
        float s = fcb[1120 + c];
        for (int p = 0; p < 14; ++p) s += sa[p]*fcb[1050 + c*14 + p];
        out[b*C_ + c] = s;
    }
}

extern "C" void kernel_launch(void* const* d_in, const int* in_sizes, int n_in,
                              void* d_out, int out_size, void* d_ws, size_t ws_size,
                              hipStream_t stream) {
    (void)in_sizes; (void)n_in; (void)out_size; (void)ws_size;
    const float* tex   = (const float*)d_in[0];
    const float* fp    = (const float*)d_in[1];
    const float* eot   = (const float*)d_in[2];
    const float* fcond = (const float*)d_in[3];
    const float* qw    = (const float*)d_in[4];
    const float* qb    = (const float*)d_in[5];
    const float* cw    = (const float*)d_in[6];
    const float* cb    = (const float*)d_in[7];
    const float* w1c   = (const float*)d_in[8];  const float* b1c = (const float*)d_in[9];
    const float* w2c   = (const float*)d_in[10]; const float* b2c = (const float*)d_in[11];
    const float* w3c   = (const float*)d_in[12]; const float* b3c = (const float*)d_in[13];
    const float* w4c   = (const float*)d_in[14]; const float* b4c = (const float*)d_in[15];
    const float* f1bw  = (const float*)d_in[16]; const float* f1bb = (const float*)d_in[17];
    const float* f2bw  = (const float*)d_in[18]; const float* f2bb = (const float*)d_in[19];
    const float* f3bw  = (const float*)d_in[20]; const float* f3bb = (const float*)d_in[21];
    const float* f4bw  = (const float*)d_in[22]; const float* f4bb = (const float*)d_in[23];
    const float* f5ww  = (const float*)d_in[24]; const float* f5wb = (const float*)d_in[25];
    const float* f5bw  = (const float*)d_in[26]; const float* f5bb = (const float*)d_in[27];
    float* out = (float*)d_out;

    float* ws     = (float*)d_ws;
    float* Qb     = ws;                          // 81920
    float* pw     = Qb + 81920;                  // 189120
    float* part   = pw + 189120;                 // 19*81920 = 1556480
    float* pstat  = part + 1556480;              // 37*32*5*2 = 11840 (8B-aligned)
    float* cm     = pstat + 11840;               // 27440
    float* g1w    = cm + 27440;                  // 125440
    float* g2w    = g1w + 125440;                // 31360
    float* g3w    = g2w + 31360;                 // 7840
    float* g4w    = g3w + 7840;                  // 1960
    float* fcb    = g4w + 1960;                  // 1125
    float* swl    = fcb + 1125;                  // 12320

    k_front<<<1450, 256, 0, stream>>>(fcond, cw, cb, cm, out + B_*C_, fp, swl);
    k_Q<<<dim3(2, B_), 256, 0, stream>>>(fp, swl, Qb);
    k_conv_pw<<<1559, 256, 0, stream>>>(cm, w1c, b1c, w2c, b2c, w3c, b3c, w4c, b4c,
                                        g1w, g2w, g3w, g4w,
                                        f1bw, f1bb, f2bw, f2bb, f3bw, f3bb,
                                        f4bw, f4bb, f5ww, f5wb, f5bw, f5bb, fcb,
                                        tex, Qb, pw, (float2*)pstat);
    k_ftf<<<dim3(NCH_, B_), 512, 0, stream>>>(tex, pw, (const float2*)pstat, part);
    k_fq_target<<<B_*C_, 256, 0, stream>>>(part, eot, qw, qb,
                                           g1w, g2w, g3w, g4w, fcb, out);
}